// Round 5
// baseline (9334.135 us; speedup 1.0000x reference)
//
#include <hip/hip_runtime.h>
#include <hip/hip_bf16.h>
#include <math.h>

#define Bz 64
#define Sz 256
#define Dz 256
#define Hz 512
#define FH 2048   // 4H
#define OH 1024   // 2H
#define Tz 48
#define MN ((size_t)Sz*Bz)   // 16384 rows, time-major
#define EPSV 1e-5f
#define LOG2E 1.44269504f

typedef __hip_bfloat16 bf16;
typedef __attribute__((ext_vector_type(8))) short short8;
typedef __attribute__((ext_vector_type(4))) float floatx4;
typedef unsigned long long u64;

__device__ __forceinline__ float b2f(bf16 v){ return __bfloat162float(v); }
__device__ __forceinline__ float us2f(unsigned short u){ return __uint_as_float(((unsigned)u)<<16); }
__device__ __forceinline__ float fsig(float x){
  float e = __builtin_amdgcn_exp2f(-x*LOG2E);
  return __builtin_amdgcn_rcpf(1.f + e);
}
__device__ __forceinline__ float ftanh(float x){
  float e = __builtin_amdgcn_exp2f(x*(2.f*LOG2E));
  return 1.f - 2.f*__builtin_amdgcn_rcpf(e + 1.f);
}
__device__ __forceinline__ void load4f(const bf16* p, float v[4]) {
  ushort4 t = *(const ushort4*)p;
  v[0]=us2f(t.x); v[1]=us2f(t.y); v[2]=us2f(t.z); v[3]=us2f(t.w);
}
__device__ __forceinline__ void storev(float* p, float v){ *p = v; }
__device__ __forceinline__ void storev(bf16* p, float v){ *p = __float2bfloat16(v); }

// ---------- fp32 -> bf16 cast ----------
__global__ __launch_bounds__(256) void castf2b(const float* __restrict__ in, bf16* __restrict__ out, int n)
{
  int i = (blockIdx.x*256 + threadIdx.x)*4;
  if (i >= n) return;
  float4 v = *(const float4*)(in + i);
  bf16 tmp[4];
  tmp[0] = __float2bfloat16(v.x); tmp[1] = __float2bfloat16(v.y);
  tmp[2] = __float2bfloat16(v.z); tmp[3] = __float2bfloat16(v.w);
  *(uint2*)(out + i) = *(const uint2*)tmp;
}

// inputs [B][S][D] fp32 -> xT0 [s*64+b][D] bf16 (time-major)
__global__ __launch_bounds__(64) void permcast_k(const float* __restrict__ in, bf16* __restrict__ out)
{
  int b = blockIdx.x, s = blockIdx.y, tid = threadIdx.x;
  float4 v = *(const float4*)(in + ((size_t)b*Sz + s)*Dz + tid*4);
  bf16 tmp[4];
  tmp[0] = __float2bfloat16(v.x); tmp[1] = __float2bfloat16(v.y);
  tmp[2] = __float2bfloat16(v.z); tmp[3] = __float2bfloat16(v.w);
  *(uint2*)(out + ((size_t)s*Bz + b)*Dz + tid*4) = *(const uint2*)tmp;
}

__global__ __launch_bounds__(256) void bnprep_k(const float* __restrict__ gamma, const float* __restrict__ beta,
  const float* __restrict__ mean, const float* __restrict__ var,
  float* __restrict__ scale, float* __restrict__ shift)
{
  int i = blockIdx.x*256 + threadIdx.x;
  if (i >= OH) return;
  float s = gamma[i]*rsqrtf(var[i]+EPSV);
  scale[i] = s; shift[i] = beta[i] - mean[i]*s;
}

__global__ __launch_bounds__(256) void bn_k(const bf16* __restrict__ x, bf16* __restrict__ y,
  const float* __restrict__ scale, const float* __restrict__ shift)
{
  size_t n = MN*OH;
  for (size_t i = (size_t)blockIdx.x*256 + threadIdx.x; i < n; i += (size_t)gridDim.x*256) {
    int c = (int)(i & (OH-1));
    y[i] = __float2bfloat16(b2f(x[i]) * scale[c] + shift[c]);
  }
}

// ---------- MFMA bf16 GEMM: C = A(MxK) * W(NxK)^T + bias, opt relu ----------
// biasRow: bias indexed by row m (for pre^T GEMMs), else by col n.
template<typename TC>
__global__ __launch_bounds__(256) void gemm_mfma(
  const bf16* __restrict__ A, const bf16* __restrict__ W,
  const float* __restrict__ b1, const float* __restrict__ b2,
  TC* __restrict__ Cv, int M, int N, int K, int relu, int biasRow)
{
  __shared__ bf16 As[128][40];
  __shared__ bf16 Bs[128][40];
  int tid = threadIdx.x;
  int wave = tid>>6, lane = tid&63, l15 = lane&15, quad = lane>>4;
  int m0 = blockIdx.y*128, n0 = blockIdx.x*128;
  int wm = (wave>>1)*64, wn = (wave&1)*64;
  int srow = tid>>1, scw = (tid&1)*16;
  const bf16* Ap = A + (size_t)(m0+srow)*K + scw;
  const bf16* Wp = W + (size_t)(n0+srow)*K + scw;
  floatx4 zero = {0.f,0.f,0.f,0.f};
  floatx4 acc[4][4];
  #pragma unroll
  for (int i=0;i<4;i++)
    #pragma unroll
    for (int j=0;j<4;j++) acc[i][j] = zero;

  for (int k0 = 0; k0 < K; k0 += 32) {
    float4 a0 = *(const float4*)Ap, a1 = *(const float4*)(Ap+8);
    float4 w0 = *(const float4*)Wp, w1 = *(const float4*)(Wp+8);
    Ap += 32; Wp += 32;
    __syncthreads();
    *(float4*)&As[srow][scw]   = a0; *(float4*)&As[srow][scw+8] = a1;
    *(float4*)&Bs[srow][scw]   = w0; *(float4*)&Bs[srow][scw+8] = w1;
    __syncthreads();
    short8 af[4], bfv[4];
    #pragma unroll
    for (int mi=0;mi<4;mi++) af[mi]  = *(const short8*)&As[wm+mi*16+l15][quad*8];
    #pragma unroll
    for (int ni=0;ni<4;ni++) bfv[ni] = *(const short8*)&Bs[wn+ni*16+l15][quad*8];
    #pragma unroll
    for (int mi=0;mi<4;mi++)
      #pragma unroll
      for (int ni=0;ni<4;ni++)
        acc[mi][ni] = __builtin_amdgcn_mfma_f32_16x16x32_bf16(af[mi], bfv[ni], acc[mi][ni], 0,0,0);
  }
  #pragma unroll
  for (int mi=0;mi<4;mi++){
    #pragma unroll
    for (int ni=0;ni<4;ni++){
      int n = n0 + wn + ni*16 + l15;
      float bcol = biasRow ? 0.f : ((b1 ? b1[n] : 0.f) + (b2 ? b2[n] : 0.f));
      #pragma unroll
      for (int r=0;r<4;r++){
        int m = m0 + wm + mi*16 + quad*4 + r;
        float v = acc[mi][ni][r] + bcol;
        if (biasRow) v += b1[m] + b2[m];
        if (relu) v = fmaxf(v, 0.f);
        storev(&Cv[(size_t)m*N + n], v);
      }
    }
  }
}

// ---------- naive GEMM for fc3 (N=48), fp32 W ----------
__global__ __launch_bounds__(256) void gemm_nt_small(
  const bf16* __restrict__ A, const float* __restrict__ W,
  const float* __restrict__ b1, float* __restrict__ Cv, int M, int N, int K)
{
  __shared__ float As[8][128];
  __shared__ float Ws[8][128];
  int tid = threadIdx.x;
  int tx = tid & 15, ty = tid >> 4;
  int m0 = blockIdx.y * 128, n0 = blockIdx.x * 128;
  int sr = tid >> 1;
  int sk = (tid & 1) * 4;
  const bf16* Ap = A + (size_t)(m0 + sr) * K + sk;
  bool wok = (n0 + sr) < N;
  const float* Wp = W + (size_t)(wok ? (n0 + sr) : 0) * K + sk;
  float acc[8][8] = {};
  for (int k0 = 0; k0 < K; k0 += 8) {
    float av[4], wv[4];
    load4f(Ap, av);
    if (wok) { float4 t = *(const float4*)Wp; wv[0]=t.x; wv[1]=t.y; wv[2]=t.z; wv[3]=t.w; }
    else { wv[0]=wv[1]=wv[2]=wv[3]=0.f; }
    Ap += 8; Wp += 8;
    __syncthreads();
    As[sk+0][sr]=av[0]; As[sk+1][sr]=av[1]; As[sk+2][sr]=av[2]; As[sk+3][sr]=av[3];
    Ws[sk+0][sr]=wv[0]; Ws[sk+1][sr]=wv[1]; Ws[sk+2][sr]=wv[2]; Ws[sk+3][sr]=wv[3];
    __syncthreads();
    #pragma unroll
    for (int kk = 0; kk < 8; kk++) {
      float a[8], w[8];
      *(float4*)&a[0] = *(const float4*)&As[kk][ty*8];
      *(float4*)&a[4] = *(const float4*)&As[kk][ty*8+4];
      *(float4*)&w[0] = *(const float4*)&Ws[kk][tx*8];
      *(float4*)&w[4] = *(const float4*)&Ws[kk][tx*8+4];
      #pragma unroll
      for (int i=0;i<8;i++)
        #pragma unroll
        for (int j=0;j<8;j++) acc[i][j] += a[i]*w[j];
    }
  }
  #pragma unroll
  for (int i=0;i<8;i++){
    int m = m0 + ty*8 + i;
    #pragma unroll
    for (int j=0;j<8;j++){
      int n = n0 + tx*8 + j;
      if (n < N) Cv[(size_t)m*N + n] = acc[i][j] + b1[n];
    }
  }
}

// ---------- persistent BiLSTM layer ----------
// 64 blocks = dir(2, blk>>5) x jslice(32 of 16 units). Weights in LDS once.
// Waves: (mg = wave>>1 -> batch half, ng = wave&1 -> gate pair). Cross-block h via
// relaxed agent-scope (L2-bypass) atomics; per-dir slot barrier; L2 never invalidated.
__global__ __launch_bounds__(256,1) void lstm_persist(
  const bf16* __restrict__ preF, const bf16* __restrict__ preB,   // [2048][16384]
  const bf16* __restrict__ WF, const bf16* __restrict__ WB,       // Whh bf16 [2048][512]
  bf16* __restrict__ hbuf,          // [2 pp][2 dir][64][512]
  bf16* __restrict__ xT,            // [t*64+b][1024]
  int* __restrict__ slots)          // [64] zeroed
{
  __shared__ bf16 wlds[64][520];    // 16 units x 4 gates, padded rows (16B-aligned)
  __shared__ float ex[4][4][64][4]; // [m-tile][gate][lane][r] gate exchange, 16 KB
  int blk = blockIdx.x;
  int dir = blk >> 5;
  int js  = blk & 31;
  int j0  = js * 16;
  const bf16* pre = dir ? preB : preF;
  const bf16* W   = dir ? WB : WF;
  int colOff = dir ? Hz : 0;
  int tid = threadIdx.x;
  int wave = tid >> 6, lane = tid & 63, l15 = lane & 15, quad = lane >> 4;
  int mg = wave >> 1, ng = wave & 1;
  int mtg = 2*mg + ng;              // owned m-tile (batch group of 16)
  int og  = 2*(1-ng);               // partner wave's gate base

  for (int chunk = tid; chunk < 64*64; chunk += 256) {
    int n = chunk >> 6, col = (chunk & 63) * 8;
    int g = n >> 4, idx = n & 15;
    *(float4*)&wlds[n][col] = *(const float4*)(W + ((size_t)(g*512 + j0 + idx))*Hz + col);
  }
  __syncthreads();

  int j = j0 + l15;
  int bown = mtg*16 + quad*4;       // owned batch base (4 batches via r)
  float c[4] = {0.f,0.f,0.f,0.f};

  for (int t = 0; t < Sz; t++) {
    int tcur = dir ? (Sz-1-t) : t;

    // pre-activations for owned (batches, unit j), all 4 gates: 8B full-line loads
    float pg[4][4];
    #pragma unroll
    for (int g=0; g<4; g++) {
      const bf16* pp_ = pre + (size_t)(g*Hz + j)*MN + (size_t)tcur*Bz + bown;
      ushort4 pv = *(const ushort4*)pp_;
      pg[g][0]=us2f(pv.x); pg[g][1]=us2f(pv.y); pg[g][2]=us2f(pv.z); pg[g][3]=us2f(pv.w);
    }

    floatx4 zero = {0.f,0.f,0.f,0.f};
    floatx4 acc[2][2] = {{zero,zero},{zero,zero}};   // [gate-local][m-tile-local]
    if (t > 0) {
      const u64* hb_r = (const u64*)(hbuf + ((size_t)(((t&1)^1)*2 + dir))*Bz*Hz);
      #pragma unroll 4
      for (int ks=0; ks<16; ks++) {
        union { u64 u[2]; short8 s; } af[2];
        #pragma unroll
        for (int ml=0; ml<2; ml++) {
          size_t off = ((size_t)((2*mg+ml)*16 + l15)*Hz + ks*32 + quad*8) >> 2;
          af[ml].u[0] = __hip_atomic_load(hb_r + off,     __ATOMIC_RELAXED, __HIP_MEMORY_SCOPE_AGENT);
          af[ml].u[1] = __hip_atomic_load(hb_r + off + 1, __ATOMIC_RELAXED, __HIP_MEMORY_SCOPE_AGENT);
        }
        #pragma unroll
        for (int gl=0; gl<2; gl++) {
          short8 bfv = *(const short8*)&wlds[(2*ng+gl)*16 + l15][ks*32 + quad*8];
          #pragma unroll
          for (int ml=0; ml<2; ml++)
            acc[gl][ml] = __builtin_amdgcn_mfma_f32_16x16x32_bf16(af[ml].s, bfv, acc[gl][ml], 0,0,0);
        }
      }
    }

    // gate exchange: write non-owned m-tile's two gates, read partner's two gates
    __syncthreads();
    #pragma unroll
    for (int gl=0; gl<2; gl++)
      *(floatx4*)&ex[2*mg+(1-ng)][2*ng+gl][lane][0] = acc[gl][1-ng];
    __syncthreads();
    floatx4 G[4];
    G[2*ng]   = acc[0][ng];
    G[2*ng+1] = acc[1][ng];
    G[og]     = *(const floatx4*)&ex[mtg][og][lane][0];
    G[og+1]   = *(const floatx4*)&ex[mtg][og+1][lane][0];

    bf16* hb_w = hbuf + ((size_t)((t&1)*2 + dir))*Bz*Hz;
    #pragma unroll
    for (int r=0; r<4; r++) {
      int b = bown + r;
      float gi = G[0][r] + pg[0][r];
      float gf = G[1][r] + pg[1][r];
      float gg = G[2][r] + pg[2][r];
      float go = G[3][r] + pg[3][r];
      float cv = fsig(gf)*c[r] + fsig(gi)*ftanh(gg);
      float h  = fsig(go)*ftanh(cv);
      c[r] = cv;
      bf16 hv = __float2bfloat16(h);
      unsigned short hbits = *(unsigned short*)&hv;
      unsigned other = (unsigned)__shfl_xor((int)hbits, 1);
      if ((l15 & 1) == 0) {
        unsigned packed = ((unsigned)hbits) | (other << 16);
        __hip_atomic_store((unsigned*)(hb_w + (size_t)b*Hz + j), packed,
                           __ATOMIC_RELAXED, __HIP_MEMORY_SCOPE_AGENT);
        *(unsigned*)(xT + ((size_t)tcur*Bz + b)*OH + colOff + j) = packed;
      }
    }

    if (t < Sz-1) {
      __syncthreads();   // drains all waves' h stores (vmcnt(0) before s_barrier)
      if (tid == 0)
        __hip_atomic_store(&slots[dir*32 + js], t+1, __ATOMIC_RELEASE, __HIP_MEMORY_SCOPE_AGENT);
      if (tid < 64) {
        int idx = dir*32 + (lane & 31);
        bool done = false;
        do {
          int v = __hip_atomic_load(&slots[idx], __ATOMIC_RELAXED, __HIP_MEMORY_SCOPE_AGENT);
          done = __all(v > t);
          if (!done) __builtin_amdgcn_s_sleep(1);
        } while (!done);
      }
      __syncthreads();
    }
  }
}

// ---------- CRF (em is time-major: row = t*64 + b) ----------
__global__ __launch_bounds__(64) void crf_k(const float* __restrict__ em, const int* __restrict__ tags,
  const float* __restrict__ start, const float* __restrict__ endv, const float* __restrict__ trans,
  float* __restrict__ result)
{
  __shared__ float tr[Tz*Tz];
  __shared__ float alpha[2][Tz];
  int b = blockIdx.x, tid = threadIdx.x;
  for (int i = tid; i < Tz*Tz; i += 64) tr[i] = trans[i];
  float np = 0.f;
  for (int t = tid; t < Sz; t += 64) {
    int tg = tags[b*Sz + t];
    np += em[((size_t)t*Bz + b)*Tz + tg];
    if (t+1 < Sz) np += trans[tg*Tz + tags[b*Sz + t + 1]];
  }
  #pragma unroll
  for (int off = 32; off; off >>= 1) np += __shfl_down(np, off);
  float num = 0.f;
  if (tid == 0) num = np + start[tags[b*Sz]] + endv[tags[b*Sz + Sz-1]];
  if (tid < Tz) alpha[0][tid] = start[tid] + em[(size_t)b*Tz + tid];
  __syncthreads();
  int cur = 0;
  for (int t = 1; t < Sz; t++) {
    if (tid < Tz) {
      float m = -1e30f;
      for (int i = 0; i < Tz; i++) m = fmaxf(m, alpha[cur][i] + tr[i*Tz + tid]);
      float sum = 0.f;
      for (int i = 0; i < Tz; i++) sum += expf(alpha[cur][i] + tr[i*Tz + tid] - m);
      alpha[1-cur][tid] = m + logf(sum) + em[((size_t)t*Bz + b)*Tz + tid];
    }
    cur ^= 1;
    __syncthreads();
  }
  float a = (tid < Tz) ? alpha[cur][tid] + endv[tid] : -1e30f;
  float m = a;
  #pragma unroll
  for (int off = 32; off; off >>= 1) m = fmaxf(m, __shfl_down(m, off));
  m = __shfl(m, 0);
  float e = (tid < Tz) ? expf(a - m) : 0.f;
  #pragma unroll
  for (int off = 32; off; off >>= 1) e += __shfl_down(e, off);
  if (tid == 0) result[b] = num - (m + logf(e));
}

__global__ __launch_bounds__(64) void finalize_k(const float* __restrict__ result, float* __restrict__ outp)
{
  float v = result[threadIdx.x];
  #pragma unroll
  for (int off = 32; off; off >>= 1) v += __shfl_down(v, off);
  if (threadIdx.x == 0) outp[0] = -(v * (1.f/64.f));
}

extern "C" void kernel_launch(void* const* d_in, const int* in_sizes, int n_in,
                              void* d_out, int out_size, void* d_ws, size_t ws_size,
                              hipStream_t stream)
{
  (void)in_sizes; (void)n_in; (void)out_size; (void)ws_size;
  const float* inputs = (const float*)d_in[0];
  const int*   tags   = (const int*)d_in[1];
  const float* Wih[2][2] = {{(const float*)d_in[2],  (const float*)d_in[6]},
                            {(const float*)d_in[10], (const float*)d_in[14]}};
  const float* Whh[2][2] = {{(const float*)d_in[3],  (const float*)d_in[7]},
                            {(const float*)d_in[11], (const float*)d_in[15]}};
  const float* bih[2][2] = {{(const float*)d_in[4],  (const float*)d_in[8]},
                            {(const float*)d_in[12], (const float*)d_in[16]}};
  const float* bhh[2][2] = {{(const float*)d_in[5],  (const float*)d_in[9]},
                            {(const float*)d_in[13], (const float*)d_in[17]}};
  const float* bn_gamma = (const float*)d_in[18];
  const float* bn_beta  = (const float*)d_in[19];
  const float* bn_mean  = (const float*)d_in[20];
  const float* bn_var   = (const float*)d_in[21];
  const float* fc1_w = (const float*)d_in[22];
  const float* fc1_b = (const float*)d_in[23];
  const float* fc2_w = (const float*)d_in[24];
  const float* fc2_b = (const float*)d_in[25];
  const float* fc3_w = (const float*)d_in[26];
  const float* fc3_b = (const float*)d_in[27];
  const float* crf_start = (const float*)d_in[28];
  const float* crf_end   = (const float*)d_in[29];
  const float* crf_trans = (const float*)d_in[30];

  char* p = (char*)d_ws;
  auto alloc = [&](size_t bytes) { char* r = p; p += (bytes + 255) & ~(size_t)255; return r; };
  bf16*  preTF = (bf16*) alloc((size_t)FH*MN*sizeof(bf16));   // 64 MB [gate-unit][t*64+b]
  bf16*  preTB = (bf16*) alloc((size_t)FH*MN*sizeof(bf16));   // 64 MB
  bf16*  xT    = (bf16*) alloc(MN*OH*sizeof(bf16));           // 32 MB time-major x
  bf16*  xbn   = (bf16*) alloc(MN*OH*sizeof(bf16));           // 32 MB BN(x)
  bf16*  xT0   = (bf16*) alloc(MN*Dz*sizeof(bf16));           // 8 MB (em overlays later)
  bf16*  Wih0A = (bf16*) alloc((size_t)FH*Dz*sizeof(bf16));
  bf16*  Wih0B = (bf16*) alloc((size_t)FH*Dz*sizeof(bf16));
  bf16*  Wih1A = (bf16*) alloc((size_t)FH*OH*sizeof(bf16));
  bf16*  Wih1B = (bf16*) alloc((size_t)FH*OH*sizeof(bf16));
  bf16*  Whh0A = (bf16*) alloc((size_t)FH*Hz*sizeof(bf16));
  bf16*  Whh0B = (bf16*) alloc((size_t)FH*Hz*sizeof(bf16));
  bf16*  Whh1A = (bf16*) alloc((size_t)FH*Hz*sizeof(bf16));
  bf16*  Whh1B = (bf16*) alloc((size_t)FH*Hz*sizeof(bf16));
  bf16*  fc1wb = (bf16*) alloc((size_t)Hz*OH*sizeof(bf16));
  bf16*  fc2wb = (bf16*) alloc((size_t)256*Hz*sizeof(bf16));
  bf16*  hbuf  = (bf16*) alloc(4*(size_t)Bz*Hz*sizeof(bf16)); // 256 KB ping-pong
  int*   slots = (int*)  alloc(128*sizeof(int));
  float* bnscale = (float*)alloc(OH*sizeof(float));
  float* bnshift = (float*)alloc(OH*sizeof(float));
  float* result  = (float*)alloc(Bz*sizeof(float));
  float* em   = (float*)xT0;                                  // overlay (3 MB <= 8 MB)
  bf16* fc1o = (bf16*)preTF;                                  // overlays after recurrence
  bf16* fc2o = (bf16*)preTB;

  dim3 tb(256);
  auto cast = [&](const float* src, bf16* dst, size_t n){
    castf2b<<<(n/4 + 255)/256, tb, 0, stream>>>(src, dst, (int)n);
  };

  hipMemsetAsync(slots, 0, 128*sizeof(int), stream);
  permcast_k<<<dim3(Bz, Sz), 64, 0, stream>>>(inputs, xT0);
  cast(Wih[0][0], Wih0A, (size_t)FH*Dz);
  cast(Wih[0][1], Wih0B, (size_t)FH*Dz);
  cast(Wih[1][0], Wih1A, (size_t)FH*OH);
  cast(Wih[1][1], Wih1B, (size_t)FH*OH);
  cast(Whh[0][0], Whh0A, (size_t)FH*Hz);
  cast(Whh[0][1], Whh0B, (size_t)FH*Hz);
  cast(Whh[1][0], Whh1A, (size_t)FH*Hz);
  cast(Whh[1][1], Whh1B, (size_t)FH*Hz);
  cast(fc1_w, fc1wb, (size_t)Hz*OH);
  cast(fc2_w, fc2wb, (size_t)256*Hz);
  bnprep_k<<<OH/256, tb, 0, stream>>>(bn_gamma, bn_beta, bn_mean, bn_var, bnscale, bnshift);

  // ---- layer 0: pre^T = Wih (2048 x K) x xT0^T -> [2048][16384], bias by row ----
  gemm_mfma<bf16><<<dim3(MN/128, FH/128), tb, 0, stream>>>(Wih0A, xT0, bih[0][0], bhh[0][0], preTF, FH, MN, Dz, 0, 1);
  gemm_mfma<bf16><<<dim3(MN/128, FH/128), tb, 0, stream>>>(Wih0B, xT0, bih[0][1], bhh[0][1], preTB, FH, MN, Dz, 0, 1);
  lstm_persist<<<64, tb, 0, stream>>>(preTF, preTB, Whh0A, Whh0B, hbuf, xT, slots);
  // ---- layer 1 ----
  gemm_mfma<bf16><<<dim3(MN/128, FH/128), tb, 0, stream>>>(Wih1A, xT, bih[1][0], bhh[1][0], preTF, FH, MN, OH, 0, 1);
  gemm_mfma<bf16><<<dim3(MN/128, FH/128), tb, 0, stream>>>(Wih1B, xT, bih[1][1], bhh[1][1], preTB, FH, MN, OH, 0, 1);
  lstm_persist<<<64, tb, 0, stream>>>(preTF, preTB, Whh1A, Whh1B, hbuf, xT, slots + 64);
  // ---- head ----
  bn_k<<<2048, tb, 0, stream>>>(xT, xbn, bnscale, bnshift);
  gemm_mfma<bf16><<<dim3(Hz/128, MN/128), tb, 0, stream>>>(xbn, fc1wb, fc1_b, nullptr, fc1o, MN, Hz, OH, 1, 0);
  gemm_mfma<bf16><<<dim3(256/128, MN/128), tb, 0, stream>>>(fc1o, fc2wb, fc2_b, nullptr, fc2o, MN, 256, Hz, 1, 0);
  gemm_nt_small<<<dim3(1, MN/128), tb, 0, stream>>>(fc2o, fc3_w, fc3_b, em, MN, Tz, 256);
  crf_k<<<Bz, 64, 0, stream>>>(em, tags, crf_start, crf_end, crf_trans, result);
  finalize_k<<<1, 64, 0, stream>>>(result, (float*)d_out);
}

// Round 6
// 5804.420 us; speedup vs baseline: 1.6081x; 1.6081x over previous
//
#include <hip/hip_runtime.h>
#include <hip/hip_bf16.h>
#include <math.h>

#define Bz 64
#define Sz 256
#define Dz 256
#define Hz 512
#define FH 2048   // 4H
#define OH 1024   // 2H
#define Tz 48
#define MN ((size_t)Sz*Bz)   // 16384 rows, time-major
#define EPSV 1e-5f
#define LOG2E 1.44269504f

typedef __hip_bfloat16 bf16;
typedef __attribute__((ext_vector_type(8))) short short8;
typedef __attribute__((ext_vector_type(4))) float floatx4;
typedef unsigned long long u64;

__device__ __forceinline__ float b2f(bf16 v){ return __bfloat162float(v); }
__device__ __forceinline__ float us2f(unsigned short u){ return __uint_as_float(((unsigned)u)<<16); }
__device__ __forceinline__ float fsig(float x){
  float e = __builtin_amdgcn_exp2f(-x*LOG2E);
  return __builtin_amdgcn_rcpf(1.f + e);
}
__device__ __forceinline__ float ftanh(float x){
  float e = __builtin_amdgcn_exp2f(x*(2.f*LOG2E));
  return 1.f - 2.f*__builtin_amdgcn_rcpf(e + 1.f);
}
__device__ __forceinline__ void load4f(const bf16* p, float v[4]) {
  ushort4 t = *(const ushort4*)p;
  v[0]=us2f(t.x); v[1]=us2f(t.y); v[2]=us2f(t.z); v[3]=us2f(t.w);
}
__device__ __forceinline__ void storev(float* p, float v){ *p = v; }
__device__ __forceinline__ void storev(bf16* p, float v){ *p = __float2bfloat16(v); }

// 8 coherent (agent-scope, L2-bypass) 16B loads, issued together, no wait.
#define LD8_COHERENT(T, A) \
  asm volatile( \
    "global_load_dwordx4 %0, %8, off sc0 sc1\n\t" \
    "global_load_dwordx4 %1, %9, off sc0 sc1\n\t" \
    "global_load_dwordx4 %2, %10, off sc0 sc1\n\t" \
    "global_load_dwordx4 %3, %11, off sc0 sc1\n\t" \
    "global_load_dwordx4 %4, %12, off sc0 sc1\n\t" \
    "global_load_dwordx4 %5, %13, off sc0 sc1\n\t" \
    "global_load_dwordx4 %6, %14, off sc0 sc1\n\t" \
    "global_load_dwordx4 %7, %15, off sc0 sc1" \
    : "=v"((T)[0]),"=v"((T)[1]),"=v"((T)[2]),"=v"((T)[3]), \
      "=v"((T)[4]),"=v"((T)[5]),"=v"((T)[6]),"=v"((T)[7]) \
    : "v"(A),"v"((A)+256),"v"((A)+512),"v"((A)+768), \
      "v"((A)+1024),"v"((A)+1280),"v"((A)+1536),"v"((A)+1792))

// ---------- fp32 -> bf16 cast ----------
__global__ __launch_bounds__(256) void castf2b(const float* __restrict__ in, bf16* __restrict__ out, int n)
{
  int i = (blockIdx.x*256 + threadIdx.x)*4;
  if (i >= n) return;
  float4 v = *(const float4*)(in + i);
  bf16 tmp[4];
  tmp[0] = __float2bfloat16(v.x); tmp[1] = __float2bfloat16(v.y);
  tmp[2] = __float2bfloat16(v.z); tmp[3] = __float2bfloat16(v.w);
  *(uint2*)(out + i) = *(const uint2*)tmp;
}

// inputs [B][S][D] fp32 -> xT0 [s*64+b][D] bf16 (time-major)
__global__ __launch_bounds__(64) void permcast_k(const float* __restrict__ in, bf16* __restrict__ out)
{
  int b = blockIdx.x, s = blockIdx.y, tid = threadIdx.x;
  float4 v = *(const float4*)(in + ((size_t)b*Sz + s)*Dz + tid*4);
  bf16 tmp[4];
  tmp[0] = __float2bfloat16(v.x); tmp[1] = __float2bfloat16(v.y);
  tmp[2] = __float2bfloat16(v.z); tmp[3] = __float2bfloat16(v.w);
  *(uint2*)(out + ((size_t)s*Bz + b)*Dz + tid*4) = *(const uint2*)tmp;
}

__global__ __launch_bounds__(256) void bnprep_k(const float* __restrict__ gamma, const float* __restrict__ beta,
  const float* __restrict__ mean, const float* __restrict__ var,
  float* __restrict__ scale, float* __restrict__ shift)
{
  int i = blockIdx.x*256 + threadIdx.x;
  if (i >= OH) return;
  float s = gamma[i]*rsqrtf(var[i]+EPSV);
  scale[i] = s; shift[i] = beta[i] - mean[i]*s;
}

__global__ __launch_bounds__(256) void bn_k(const bf16* __restrict__ x, bf16* __restrict__ y,
  const float* __restrict__ scale, const float* __restrict__ shift)
{
  size_t n = MN*OH;
  for (size_t i = (size_t)blockIdx.x*256 + threadIdx.x; i < n; i += (size_t)gridDim.x*256) {
    int c = (int)(i & (OH-1));
    y[i] = __float2bfloat16(b2f(x[i]) * scale[c] + shift[c]);
  }
}

// ---------- MFMA bf16 GEMM: C = A(MxK) * W(NxK)^T + bias, opt relu ----------
template<typename TC>
__global__ __launch_bounds__(256) void gemm_mfma(
  const bf16* __restrict__ A, const bf16* __restrict__ W,
  const float* __restrict__ b1, const float* __restrict__ b2,
  TC* __restrict__ Cv, int M, int N, int K, int relu, int biasRow)
{
  __shared__ bf16 As[128][40];
  __shared__ bf16 Bs[128][40];
  int tid = threadIdx.x;
  int wave = tid>>6, lane = tid&63, l15 = lane&15, quad = lane>>4;
  int m0 = blockIdx.y*128, n0 = blockIdx.x*128;
  int wm = (wave>>1)*64, wn = (wave&1)*64;
  int srow = tid>>1, scw = (tid&1)*16;
  const bf16* Ap = A + (size_t)(m0+srow)*K + scw;
  const bf16* Wp = W + (size_t)(n0+srow)*K + scw;
  floatx4 zero = {0.f,0.f,0.f,0.f};
  floatx4 acc[4][4];
  #pragma unroll
  for (int i=0;i<4;i++)
    #pragma unroll
    for (int j=0;j<4;j++) acc[i][j] = zero;

  for (int k0 = 0; k0 < K; k0 += 32) {
    float4 a0 = *(const float4*)Ap, a1 = *(const float4*)(Ap+8);
    float4 w0 = *(const float4*)Wp, w1 = *(const float4*)(Wp+8);
    Ap += 32; Wp += 32;
    __syncthreads();
    *(float4*)&As[srow][scw]   = a0; *(float4*)&As[srow][scw+8] = a1;
    *(float4*)&Bs[srow][scw]   = w0; *(float4*)&Bs[srow][scw+8] = w1;
    __syncthreads();
    short8 af[4], bfv[4];
    #pragma unroll
    for (int mi=0;mi<4;mi++) af[mi]  = *(const short8*)&As[wm+mi*16+l15][quad*8];
    #pragma unroll
    for (int ni=0;ni<4;ni++) bfv[ni] = *(const short8*)&Bs[wn+ni*16+l15][quad*8];
    #pragma unroll
    for (int mi=0;mi<4;mi++)
      #pragma unroll
      for (int ni=0;ni<4;ni++)
        acc[mi][ni] = __builtin_amdgcn_mfma_f32_16x16x32_bf16(af[mi], bfv[ni], acc[mi][ni], 0,0,0);
  }
  #pragma unroll
  for (int mi=0;mi<4;mi++){
    #pragma unroll
    for (int ni=0;ni<4;ni++){
      int n = n0 + wn + ni*16 + l15;
      float bcol = biasRow ? 0.f : ((b1 ? b1[n] : 0.f) + (b2 ? b2[n] : 0.f));
      #pragma unroll
      for (int r=0;r<4;r++){
        int m = m0 + wm + mi*16 + quad*4 + r;
        float v = acc[mi][ni][r] + bcol;
        if (biasRow) v += b1[m] + b2[m];
        if (relu) v = fmaxf(v, 0.f);
        storev(&Cv[(size_t)m*N + n], v);
      }
    }
  }
}

// ---------- naive GEMM for fc3 (N=48), fp32 W ----------
__global__ __launch_bounds__(256) void gemm_nt_small(
  const bf16* __restrict__ A, const float* __restrict__ W,
  const float* __restrict__ b1, float* __restrict__ Cv, int M, int N, int K)
{
  __shared__ float As[8][128];
  __shared__ float Ws[8][128];
  int tid = threadIdx.x;
  int tx = tid & 15, ty = tid >> 4;
  int m0 = blockIdx.y * 128, n0 = blockIdx.x * 128;
  int sr = tid >> 1;
  int sk = (tid & 1) * 4;
  const bf16* Ap = A + (size_t)(m0 + sr) * K + sk;
  bool wok = (n0 + sr) < N;
  const float* Wp = W + (size_t)(wok ? (n0 + sr) : 0) * K + sk;
  float acc[8][8] = {};
  for (int k0 = 0; k0 < K; k0 += 8) {
    float av[4], wv[4];
    load4f(Ap, av);
    if (wok) { float4 t = *(const float4*)Wp; wv[0]=t.x; wv[1]=t.y; wv[2]=t.z; wv[3]=t.w; }
    else { wv[0]=wv[1]=wv[2]=wv[3]=0.f; }
    Ap += 8; Wp += 8;
    __syncthreads();
    As[sk+0][sr]=av[0]; As[sk+1][sr]=av[1]; As[sk+2][sr]=av[2]; As[sk+3][sr]=av[3];
    Ws[sk+0][sr]=wv[0]; Ws[sk+1][sr]=wv[1]; Ws[sk+2][sr]=wv[2]; Ws[sk+3][sr]=wv[3];
    __syncthreads();
    #pragma unroll
    for (int kk = 0; kk < 8; kk++) {
      float a[8], w[8];
      *(float4*)&a[0] = *(const float4*)&As[kk][ty*8];
      *(float4*)&a[4] = *(const float4*)&As[kk][ty*8+4];
      *(float4*)&w[0] = *(const float4*)&Ws[kk][tx*8];
      *(float4*)&w[4] = *(const float4*)&Ws[kk][tx*8+4];
      #pragma unroll
      for (int i=0;i<8;i++)
        #pragma unroll
        for (int j=0;j<8;j++) acc[i][j] += a[i]*w[j];
    }
  }
  #pragma unroll
  for (int i=0;i<8;i++){
    int m = m0 + ty*8 + i;
    #pragma unroll
    for (int j=0;j<8;j++){
      int n = n0 + tx*8 + j;
      if (n < N) Cv[(size_t)m*N + n] = acc[i][j] + b1[n];
    }
  }
}

// ---------- persistent BiLSTM layer ----------
// 64 blocks = dir(2) x jslice(32 of 16 units). Weights in LDS once; h staged to LDS
// each step via bulk coherent (sc0 sc1) dwordx4 loads; cross-block h stores are
// relaxed agent atomics (write-through); slot barrier with RELAXED publish
// (vmcnt(0) at __syncthreads already committed write-through stores to L3).
__global__ __launch_bounds__(256,1) void lstm_persist(
  const bf16* __restrict__ preF, const bf16* __restrict__ preB,   // [2048][16384]
  const bf16* __restrict__ WF, const bf16* __restrict__ WB,       // Whh bf16 [2048][512]
  bf16* __restrict__ hbuf,          // [2 pp][2 dir][64][512]
  bf16* __restrict__ xT,            // [t*64+b][1024]
  int* __restrict__ slots)          // [64] zeroed
{
  __shared__ bf16 wlds[64][520];    // 16 units x 4 gates x 512 K, padded rows
  __shared__ bf16 hstage[64][520];  // 64 batches x 512 K, padded rows
  __shared__ float ex[4][4][4][64]; // [m-tile][gate][r][lane] b32-friendly exchange
  int blk = blockIdx.x;
  int dir = blk >> 5;
  int js  = blk & 31;
  int j0  = js * 16;
  const bf16* pre = dir ? preB : preF;
  const bf16* W   = dir ? WB : WF;
  int colOff = dir ? Hz : 0;
  int tid = threadIdx.x;
  int wave = tid >> 6, lane = tid & 63, l15 = lane & 15, quad = lane >> 4;
  int mg = wave >> 1, ng = wave & 1;
  int mtg = 2*mg + ng;              // owned m-tile (16 batches)
  int og  = 2*(1-ng);               // partner wave's gate base

  for (int chunk = tid; chunk < 64*64; chunk += 256) {
    int n = chunk >> 6, col = (chunk & 63) * 8;
    int g = n >> 4, idx = n & 15;
    *(float4*)&wlds[n][col] = *(const float4*)(W + ((size_t)(g*512 + j0 + idx))*Hz + col);
  }
  __syncthreads();

  int j = j0 + l15;
  int bown = mtg*16 + quad*4;       // owned batch base (4 via r)
  float c[4] = {0.f,0.f,0.f,0.f};
  floatx4 zero = {0.f,0.f,0.f,0.f};

  for (int t = 0; t < Sz; t++) {
    int tcur = dir ? (Sz-1-t) : t;

    // pre-activations for owned (batches, unit j), all 4 gates (8B row-contig loads)
    float pg[4][4];
    #pragma unroll
    for (int g=0; g<4; g++) {
      const bf16* pp_ = pre + (size_t)(g*Hz + j)*MN + (size_t)tcur*Bz + bown;
      ushort4 pv = *(const ushort4*)pp_;
      pg[g][0]=us2f(pv.x); pg[g][1]=us2f(pv.y); pg[g][2]=us2f(pv.z); pg[g][3]=us2f(pv.w);
    }

    floatx4 G[4];
    if (t > 0) {
      // ---- bulk coherent stage of h_{t-1} into LDS: 16x 16B loads in flight ----
      const float4* hp = (const float4*)(hbuf + ((size_t)(((t&1)^1)*2 + dir))*Bz*Hz) + tid;
      float4 tmp[16];
      LD8_COHERENT(tmp, hp);
      LD8_COHERENT(tmp+8, hp+2048);
      asm volatile("s_waitcnt vmcnt(0)" ::: "memory");
      #pragma unroll
      for (int i=0;i<16;i++){
        int chunk = tid + i*256;
        int b = chunk >> 6, cc = (chunk & 63) * 8;
        *(float4*)&hstage[b][cc] = tmp[i];
      }
      __syncthreads();

      floatx4 acc[2][2] = {{zero,zero},{zero,zero}};   // [gate-local][m-tile-local]
      #pragma unroll
      for (int ks=0; ks<16; ks++) {
        short8 af0 = *(const short8*)&hstage[(2*mg)*16   + l15][ks*32 + quad*8];
        short8 af1 = *(const short8*)&hstage[(2*mg+1)*16 + l15][ks*32 + quad*8];
        #pragma unroll
        for (int gl=0; gl<2; gl++) {
          short8 bfv = *(const short8*)&wlds[(2*ng+gl)*16 + l15][ks*32 + quad*8];
          acc[gl][0] = __builtin_amdgcn_mfma_f32_16x16x32_bf16(af0, bfv, acc[gl][0], 0,0,0);
          acc[gl][1] = __builtin_amdgcn_mfma_f32_16x16x32_bf16(af1, bfv, acc[gl][1], 0,0,0);
        }
      }
      // gate exchange: give non-owned m-tile's two gates to its owner wave
      #pragma unroll
      for (int gl=0; gl<2; gl++)
        #pragma unroll
        for (int r=0; r<4; r++)
          ex[2*mg+(1-ng)][2*ng+gl][r][lane] = acc[gl][1-ng][r];
      __syncthreads();
      G[2*ng]   = acc[0][ng];
      G[2*ng+1] = acc[1][ng];
      #pragma unroll
      for (int r=0; r<4; r++) { G[og][r] = ex[mtg][og][r][lane]; G[og+1][r] = ex[mtg][og+1][r][lane]; }
    } else {
      G[0]=zero; G[1]=zero; G[2]=zero; G[3]=zero;
    }

    bf16* hb_w = hbuf + ((size_t)((t&1)*2 + dir))*Bz*Hz;
    #pragma unroll
    for (int r=0; r<4; r++) {
      int b = bown + r;
      float gi = G[0][r] + pg[0][r];
      float gf = G[1][r] + pg[1][r];
      float gg = G[2][r] + pg[2][r];
      float go = G[3][r] + pg[3][r];
      float cv = fsig(gf)*c[r] + fsig(gi)*ftanh(gg);
      float h  = fsig(go)*ftanh(cv);
      c[r] = cv;
      bf16 hv = __float2bfloat16(h);
      unsigned short hbits = *(unsigned short*)&hv;
      unsigned other = (unsigned)__shfl_xor((int)hbits, 1);
      if ((l15 & 1) == 0) {
        unsigned packed = ((unsigned)hbits) | (other << 16);
        __hip_atomic_store((unsigned*)(hb_w + (size_t)b*Hz + j), packed,
                           __ATOMIC_RELAXED, __HIP_MEMORY_SCOPE_AGENT);
        __hip_atomic_store((unsigned*)(xT + ((size_t)tcur*Bz + b)*OH + colOff + j), packed,
                           __ATOMIC_RELAXED, __HIP_MEMORY_SCOPE_AGENT);
      }
    }

    if (t < Sz-1) {
      __syncthreads();   // vmcnt(0): write-through h stores committed at L3
      if (tid == 0)
        __hip_atomic_store(&slots[dir*32 + js], t+1, __ATOMIC_RELAXED, __HIP_MEMORY_SCOPE_AGENT);
      if (tid < 64) {
        int idx = dir*32 + (lane & 31);
        bool done = false;
        do {
          int v = __hip_atomic_load(&slots[idx], __ATOMIC_RELAXED, __HIP_MEMORY_SCOPE_AGENT);
          done = __all(v > t);
          if (!done) __builtin_amdgcn_s_sleep(1);
        } while (!done);
      }
      __syncthreads();
    }
  }
}

// ---------- CRF (em time-major: row = t*64 + b) ----------
__global__ __launch_bounds__(64) void crf_k(const float* __restrict__ em, const int* __restrict__ tags,
  const float* __restrict__ start, const float* __restrict__ endv, const float* __restrict__ trans,
  float* __restrict__ result)
{
  __shared__ float tr[Tz*Tz];
  __shared__ float alpha[2][Tz];
  int b = blockIdx.x, tid = threadIdx.x;
  for (int i = tid; i < Tz*Tz; i += 64) tr[i] = trans[i];
  float np = 0.f;
  for (int t = tid; t < Sz; t += 64) {
    int tg = tags[b*Sz + t];
    np += em[((size_t)t*Bz + b)*Tz + tg];
    if (t+1 < Sz) np += trans[tg*Tz + tags[b*Sz + t + 1]];
  }
  #pragma unroll
  for (int off = 32; off; off >>= 1) np += __shfl_down(np, off);
  float num = 0.f;
  if (tid == 0) num = np + start[tags[b*Sz]] + endv[tags[b*Sz + Sz-1]];
  if (tid < Tz) alpha[0][tid] = start[tid] + em[(size_t)b*Tz + tid];
  __syncthreads();
  int cur = 0;
  for (int t = 1; t < Sz; t++) {
    if (tid < Tz) {
      float m = -1e30f;
      for (int i = 0; i < Tz; i++) m = fmaxf(m, alpha[cur][i] + tr[i*Tz + tid]);
      float sum = 0.f;
      for (int i = 0; i < Tz; i++) sum += expf(alpha[cur][i] + tr[i*Tz + tid] - m);
      alpha[1-cur][tid] = m + logf(sum) + em[((size_t)t*Bz + b)*Tz + tid];
    }
    cur ^= 1;
    __syncthreads();
  }
  float a = (tid < Tz) ? alpha[cur][tid] + endv[tid] : -1e30f;
  float m = a;
  #pragma unroll
  for (int off = 32; off; off >>= 1) m = fmaxf(m, __shfl_down(m, off));
  m = __shfl(m, 0);
  float e = (tid < Tz) ? expf(a - m) : 0.f;
  #pragma unroll
  for (int off = 32; off; off >>= 1) e += __shfl_down(e, off);
  if (tid == 0) result[b] = num - (m + logf(e));
}

__global__ __launch_bounds__(64) void finalize_k(const float* __restrict__ result, float* __restrict__ outp)
{
  float v = result[threadIdx.x];
  #pragma unroll
  for (int off = 32; off; off >>= 1) v += __shfl_down(v, off);
  if (threadIdx.x == 0) outp[0] = -(v * (1.f/64.f));
}

extern "C" void kernel_launch(void* const* d_in, const int* in_sizes, int n_in,
                              void* d_out, int out_size, void* d_ws, size_t ws_size,
                              hipStream_t stream)
{
  (void)in_sizes; (void)n_in; (void)out_size; (void)ws_size;
  const float* inputs = (const float*)d_in[0];
  const int*   tags   = (const int*)d_in[1];
  const float* Wih[2][2] = {{(const float*)d_in[2],  (const float*)d_in[6]},
                            {(const float*)d_in[10], (const float*)d_in[14]}};
  const float* Whh[2][2] = {{(const float*)d_in[3],  (const float*)d_in[7]},
                            {(const float*)d_in[11], (const float*)d_in[15]}};
  const float* bih[2][2] = {{(const float*)d_in[4],  (const float*)d_in[8]},
                            {(const float*)d_in[12], (const float*)d_in[16]}};
  const float* bhh[2][2] = {{(const float*)d_in[5],  (const float*)d_in[9]},
                            {(const float*)d_in[13], (const float*)d_in[17]}};
  const float* bn_gamma = (const float*)d_in[18];
  const float* bn_beta  = (const float*)d_in[19];
  const float* bn_mean  = (const float*)d_in[20];
  const float* bn_var   = (const float*)d_in[21];
  const float* fc1_w = (const float*)d_in[22];
  const float* fc1_b = (const float*)d_in[23];
  const float* fc2_w = (const float*)d_in[24];
  const float* fc2_b = (const float*)d_in[25];
  const float* fc3_w = (const float*)d_in[26];
  const float* fc3_b = (const float*)d_in[27];
  const float* crf_start = (const float*)d_in[28];
  const float* crf_end   = (const float*)d_in[29];
  const float* crf_trans = (const float*)d_in[30];

  char* p = (char*)d_ws;
  auto alloc = [&](size_t bytes) { char* r = p; p += (bytes + 255) & ~(size_t)255; return r; };
  bf16*  preTF = (bf16*) alloc((size_t)FH*MN*sizeof(bf16));   // 64 MB
  bf16*  preTB = (bf16*) alloc((size_t)FH*MN*sizeof(bf16));   // 64 MB
  bf16*  xT    = (bf16*) alloc(MN*OH*sizeof(bf16));           // 32 MB
  bf16*  xbn   = (bf16*) alloc(MN*OH*sizeof(bf16));           // 32 MB
  bf16*  xT0   = (bf16*) alloc(MN*Dz*sizeof(bf16));           // 8 MB (em overlays later)
  bf16*  Wih0A = (bf16*) alloc((size_t)FH*Dz*sizeof(bf16));
  bf16*  Wih0B = (bf16*) alloc((size_t)FH*Dz*sizeof(bf16));
  bf16*  Wih1A = (bf16*) alloc((size_t)FH*OH*sizeof(bf16));
  bf16*  Wih1B = (bf16*) alloc((size_t)FH*OH*sizeof(bf16));
  bf16*  Whh0A = (bf16*) alloc((size_t)FH*Hz*sizeof(bf16));
  bf16*  Whh0B = (bf16*) alloc((size_t)FH*Hz*sizeof(bf16));
  bf16*  Whh1A = (bf16*) alloc((size_t)FH*Hz*sizeof(bf16));
  bf16*  Whh1B = (bf16*) alloc((size_t)FH*Hz*sizeof(bf16));
  bf16*  fc1wb = (bf16*) alloc((size_t)Hz*OH*sizeof(bf16));
  bf16*  fc2wb = (bf16*) alloc((size_t)256*Hz*sizeof(bf16));
  bf16*  hbuf  = (bf16*) alloc(4*(size_t)Bz*Hz*sizeof(bf16)); // 256 KB ping-pong
  int*   slots = (int*)  alloc(128*sizeof(int));
  float* bnscale = (float*)alloc(OH*sizeof(float));
  float* bnshift = (float*)alloc(OH*sizeof(float));
  float* result  = (float*)alloc(Bz*sizeof(float));
  float* em   = (float*)xT0;
  bf16* fc1o = (bf16*)preTF;
  bf16* fc2o = (bf16*)preTB;

  dim3 tb(256);
  auto cast = [&](const float* src, bf16* dst, size_t n){
    castf2b<<<(n/4 + 255)/256, tb, 0, stream>>>(src, dst, (int)n);
  };

  hipMemsetAsync(slots, 0, 128*sizeof(int), stream);
  permcast_k<<<dim3(Bz, Sz), 64, 0, stream>>>(inputs, xT0);
  cast(Wih[0][0], Wih0A, (size_t)FH*Dz);
  cast(Wih[0][1], Wih0B, (size_t)FH*Dz);
  cast(Wih[1][0], Wih1A, (size_t)FH*OH);
  cast(Wih[1][1], Wih1B, (size_t)FH*OH);
  cast(Whh[0][0], Whh0A, (size_t)FH*Hz);
  cast(Whh[0][1], Whh0B, (size_t)FH*Hz);
  cast(Whh[1][0], Whh1A, (size_t)FH*Hz);
  cast(Whh[1][1], Whh1B, (size_t)FH*Hz);
  cast(fc1_w, fc1wb, (size_t)Hz*OH);
  cast(fc2_w, fc2wb, (size_t)256*Hz);
  bnprep_k<<<OH/256, tb, 0, stream>>>(bn_gamma, bn_beta, bn_mean, bn_var, bnscale, bnshift);

  // ---- layer 0: pre^T = Wih x xT0^T -> [2048][16384], bias by row ----
  gemm_mfma<bf16><<<dim3(MN/128, FH/128), tb, 0, stream>>>(Wih0A, xT0, bih[0][0], bhh[0][0], preTF, FH, MN, Dz, 0, 1);
  gemm_mfma<bf16><<<dim3(MN/128, FH/128), tb, 0, stream>>>(Wih0B, xT0, bih[0][1], bhh[0][1], preTB, FH, MN, Dz, 0, 1);
  lstm_persist<<<64, tb, 0, stream>>>(preTF, preTB, Whh0A, Whh0B, hbuf, xT, slots);
  // ---- layer 1 ----
  gemm_mfma<bf16><<<dim3(MN/128, FH/128), tb, 0, stream>>>(Wih1A, xT, bih[1][0], bhh[1][0], preTF, FH, MN, OH, 0, 1);
  gemm_mfma<bf16><<<dim3(MN/128, FH/128), tb, 0, stream>>>(Wih1B, xT, bih[1][1], bhh[1][1], preTB, FH, MN, OH, 0, 1);
  lstm_persist<<<64, tb, 0, stream>>>(preTF, preTB, Whh1A, Whh1B, hbuf, xT, slots + 64);
  // ---- head ----
  bn_k<<<2048, tb, 0, stream>>>(xT, xbn, bnscale, bnshift);
  gemm_mfma<bf16><<<dim3(Hz/128, MN/128), tb, 0, stream>>>(xbn, fc1wb, fc1_b, nullptr, fc1o, MN, Hz, OH, 1, 0);
  gemm_mfma<bf16><<<dim3(256/128, MN/128), tb, 0, stream>>>(fc1o, fc2wb, fc2_b, nullptr, fc2o, MN, 256, Hz, 1, 0);
  gemm_nt_small<<<dim3(1, MN/128), tb, 0, stream>>>(fc2o, fc3_w, fc3_b, em, MN, Tz, 256);
  crf_k<<<Bz, 64, 0, stream>>>(em, tags, crf_start, crf_end, crf_trans, result);
  finalize_k<<<1, 64, 0, stream>>>(result, (float*)d_out);
}